// Round 1
// baseline (447.007 us; speedup 1.0000x reference)
//
#include <hip/hip_runtime.h>
#include <hip/hip_bf16.h>

#define N 8192
#define IN_F 512
#define OUT_F 64
#define S_SPLIT 8
#define JT (N / S_SPLIT)

typedef __attribute__((ext_vector_type(8))) short short8;
typedef __attribute__((ext_vector_type(4))) float floatx4;
typedef __attribute__((ext_vector_type(4))) int intx4;

__device__ inline short f2bf(float x) {
    __hip_bfloat16 b = __float2bfloat16(x);
    return __builtin_bit_cast(short, b);
}

// K1a: W [512][64] fp32 -> WT [64][512] bf16 (feature-major for B-fragments)
__global__ void k_wt(const float* __restrict__ W, short* __restrict__ WT) {
    int idx = blockIdx.x * 256 + threadIdx.x;   // 32768 total
    int k = idx >> 6, f = idx & 63;
    WT[f * IN_F + k] = f2bf(W[k * OUT_F + f]);
}

// K1: WH = h @ W via bf16 MFMA. Writes WH fp32 [8192][64] and WHbT bf16 [64][8192].
__global__ __launch_bounds__(256) void k_wh(const float* __restrict__ h,
                                            const short* __restrict__ WT,
                                            float* __restrict__ WH,
                                            short* __restrict__ WHbT) {
    int w = threadIdx.x >> 6;
    int lane = threadIdx.x & 63;
    int n = lane & 15, q = lane >> 4;
    int i0 = blockIdx.x * 64 + w * 16;
    int rowA = i0 + n;                       // A-fragment row (m = lane&15)
    const float* hp = h + (size_t)rowA * IN_F + q * 8;
    floatx4 acc[4] = {};
    for (int k0 = 0; k0 < IN_F; k0 += 32) {
        floatx4 h0 = *(const floatx4*)(hp + k0);
        floatx4 h1 = *(const floatx4*)(hp + k0 + 4);
        short8 af;
#pragma unroll
        for (int j = 0; j < 4; j++) { af[j] = f2bf(h0[j]); af[j + 4] = f2bf(h1[j]); }
#pragma unroll
        for (int b = 0; b < 4; b++) {
            short8 bf_ = *(const short8*)(WT + (b * 16 + n) * IN_F + k0 + q * 8);
            acc[b] = __builtin_amdgcn_mfma_f32_16x16x32_bf16(af, bf_, acc[b], 0, 0, 0);
        }
    }
    // C/D layout: col = lane&15 (=n), row = q*4 + reg
#pragma unroll
    for (int b = 0; b < 4; b++) {
#pragma unroll
        for (int r = 0; r < 4; r++) {
            int row = i0 + q * 4 + r;
            int col = b * 16 + n;
            float v = acc[b][r];
            WH[row * OUT_F + col] = v;
            WHbT[(size_t)col * N + row] = f2bf(v);
        }
    }
}

// K1b: wh1[i] = WH[i,:]·a[:64], wh2[i] = WH[i,:]·a[64:]
__global__ void k_wh12(const float* __restrict__ WH, const float* __restrict__ a,
                       float* __restrict__ wh1, float* __restrict__ wh2) {
    int row = blockIdx.x * 256 + threadIdx.x;
    float s1 = 0.f, s2 = 0.f;
#pragma unroll 8
    for (int f = 0; f < OUT_F; f++) {
        float v = WH[row * OUT_F + f];
        s1 += v * a[f];
        s2 += v * a[OUT_F + f];
    }
    wh1[row] = s1;
    wh2[row] = s2;
}

// K2: fused mask + leaky_relu + exp + (P @ WH) partial sums.
// grid (128 row-blocks, 8 j-splits), block 256 (4 waves x 16 rows each).
__global__ __launch_bounds__(256) void k_attn(const int* __restrict__ adj,
                                              const short* __restrict__ WHbT,
                                              const float* __restrict__ wh1,
                                              const float* __restrict__ wh2,
                                              float* __restrict__ num,
                                              float* __restrict__ den) {
    int w = threadIdx.x >> 6;
    int lane = threadIdx.x & 63;
    int n = lane & 15, q = lane >> 4;
    int i0 = blockIdx.x * 64 + w * 16;
    int rowA = i0 + n;                        // this lane's A-fragment row
    int j0 = blockIdx.y * JT;

    const int* ap = adj + (size_t)rowA * N + j0 + q * 8;
    const float* w2p = wh2 + j0 + q * 8;
    const short* bp0 = WHbT + (size_t)n * N + j0 + q * 8;  // + b*16*N per feature block
    float my_wh1 = wh1[rowA];

    floatx4 acc[4] = {};
    float dsum = 0.f;

    for (int t = 0; t < JT; t += 32) {
        intx4 a0 = *(const intx4*)(ap);
        intx4 a1 = *(const intx4*)(ap + 4);
        floatx4 w20 = *(const floatx4*)(w2p);
        floatx4 w21 = *(const floatx4*)(w2p + 4);
        ap += 32;
        w2p += 32;
        float p[8];
#pragma unroll
        for (int jj = 0; jj < 8; jj++) {
            int av = (jj < 4) ? a0[jj] : a1[jj - 4];
            float e = my_wh1 + ((jj < 4) ? w20[jj] : w21[jj - 4]);
            float el = fmaxf(e, 0.01f * e);        // leaky_relu
            float pv = __expf(el);
            pv = (av > 0) ? pv : 0.f;              // adjacency mask (exp(-1e9)=0)
            p[jj] = pv;
            dsum += pv;
        }
        short8 af;
#pragma unroll
        for (int jj = 0; jj < 8; jj++) af[jj] = f2bf(p[jj]);
#pragma unroll
        for (int b = 0; b < 4; b++) {
            short8 bf_ = *(const short8*)(bp0 + (size_t)b * 16 * N + t);
            acc[b] = __builtin_amdgcn_mfma_f32_16x16x32_bf16(af, bf_, acc[b], 0, 0, 0);
        }
    }

    // denominator: reduce across the 4 q-groups holding the same row (lane&15)
    dsum += __shfl_xor(dsum, 16, 64);
    dsum += __shfl_xor(dsum, 32, 64);
    if (q == 0) atomicAdd(&den[rowA], dsum);

    // numerator: C/D layout row = q*4+reg, col = b*16+n
#pragma unroll
    for (int b = 0; b < 4; b++) {
#pragma unroll
        for (int r = 0; r < 4; r++) {
            int row = i0 + q * 4 + r;
            atomicAdd(&num[row * OUT_F + b * 16 + n], acc[b][r]);
        }
    }
}

// K3: out = elu(num / den)
__global__ void k_final(const float* __restrict__ num, const float* __restrict__ den,
                        float* __restrict__ out) {
    int idx = blockIdx.x * 256 + threadIdx.x;   // 524288 total
    int row = idx >> 6;
    float x = num[idx] / den[row];
    out[idx] = (x > 0.f) ? x : (__expf(x) - 1.f);
}

extern "C" void kernel_launch(void* const* d_in, const int* in_sizes, int n_in,
                              void* d_out, int out_size, void* d_ws, size_t ws_size,
                              hipStream_t stream) {
    const float* h = (const float*)d_in[0];
    const int* adj = (const int*)d_in[1];
    const float* W = (const float*)d_in[2];
    const float* a = (const float*)d_in[3];
    float* out = (float*)d_out;

    char* ws = (char*)d_ws;
    float* WH   = (float*)(ws);                                   // 2 MB
    short* WHbT = (short*)(ws + (size_t)(2 << 20));                // 1 MB
    short* WT   = (short*)(ws + (size_t)(3 << 20));                // 64 KB
    float* wh1  = (float*)(ws + (size_t)(3 << 20) + (64 << 10));   // 32 KB
    float* wh2  = wh1 + N;                                         // 32 KB
    float* num  = (float*)(ws + (size_t)(4 << 20));                // 2 MB
    float* den  = (float*)(ws + (size_t)(6 << 20));                // 32 KB

    // zero the atomic accumulators (num + den are contiguous)
    hipMemsetAsync(ws + (size_t)(4 << 20), 0, (size_t)(2 << 20) + N * sizeof(float), stream);

    k_wt<<<dim3(128), dim3(256), 0, stream>>>(W, WT);
    k_wh<<<dim3(128), dim3(256), 0, stream>>>(h, WT, WH, WHbT);
    k_wh12<<<dim3(N / 256), dim3(256), 0, stream>>>(WH, a, wh1, wh2);
    k_attn<<<dim3(128, S_SPLIT), dim3(256), 0, stream>>>(adj, WHbT, wh1, wh2, num, den);
    k_final<<<dim3((N * OUT_F) / 256), dim3(256), 0, stream>>>(num, den, out);
}

// Round 2
// 444.532 us; speedup vs baseline: 1.0056x; 1.0056x over previous
//
#include <hip/hip_runtime.h>
#include <hip/hip_bf16.h>

#define N 8192
#define IN_F 512
#define OUT_F 64
#define S_SPLIT 16
#define JT (N / S_SPLIT)   // 512 columns per split

typedef __attribute__((ext_vector_type(8))) short short8;
typedef __attribute__((ext_vector_type(4))) float floatx4;
typedef __attribute__((ext_vector_type(4))) int intx4;

__device__ inline short f2bf(float x) {
    __hip_bfloat16 b = __float2bfloat16(x);
    return __builtin_bit_cast(short, b);
}

// K1a: W [512][64] fp32 -> WT [64][512] bf16 (feature-major for B-fragments)
__global__ void k_wt(const float* __restrict__ W, short* __restrict__ WT) {
    int idx = blockIdx.x * 256 + threadIdx.x;   // 32768 total
    int k = idx >> 6, f = idx & 63;
    WT[f * IN_F + k] = f2bf(W[k * OUT_F + f]);
}

// K1: WH = h @ W via bf16 MFMA. 512 blocks x 1 wave, 16 rows each.
// Writes WH fp32 [8192][64] and WHbT bf16 [64][8192] (LDS-staged transpose).
__global__ __launch_bounds__(64) void k_wh(const float* __restrict__ h,
                                           const short* __restrict__ WT,
                                           float* __restrict__ WH,
                                           short* __restrict__ WHbT) {
    __shared__ float tile[OUT_F][17];   // [col][row_local], +1 pad
    int lane = threadIdx.x;
    int n = lane & 15, q = lane >> 4;
    int i0 = blockIdx.x * 16;
    int rowA = i0 + n;                  // A-fragment row (m = lane&15)
    const float* hp = h + (size_t)rowA * IN_F + q * 8;
    floatx4 acc[4] = {};
    for (int k0 = 0; k0 < IN_F; k0 += 32) {
        floatx4 h0 = *(const floatx4*)(hp + k0);
        floatx4 h1 = *(const floatx4*)(hp + k0 + 4);
        short8 af;
#pragma unroll
        for (int j = 0; j < 4; j++) { af[j] = f2bf(h0[j]); af[j + 4] = f2bf(h1[j]); }
#pragma unroll
        for (int b = 0; b < 4; b++) {
            short8 bf_ = *(const short8*)(WT + (b * 16 + n) * IN_F + k0 + q * 8);
            acc[b] = __builtin_amdgcn_mfma_f32_16x16x32_bf16(af, bf_, acc[b], 0, 0, 0);
        }
    }
    // C/D layout: col = lane&15 (=n), row = q*4 + reg
#pragma unroll
    for (int b = 0; b < 4; b++) {
#pragma unroll
        for (int r = 0; r < 4; r++) {
            int rl = q * 4 + r;
            int col = b * 16 + n;
            float v = acc[b][r];
            WH[(i0 + rl) * OUT_F + col] = v;
            tile[col][rl] = v;
        }
    }
    __syncthreads();
    // phase 2: lane = col; write 16 bf16 (rows i0..i0+15) contiguous
    const float* tc = tile[lane];
    short8 s0, s1;
#pragma unroll
    for (int k = 0; k < 8; k++) { s0[k] = f2bf(tc[k]); s1[k] = f2bf(tc[k + 8]); }
    *(short8*)(WHbT + (size_t)lane * N + i0) = s0;
    *(short8*)(WHbT + (size_t)lane * N + i0 + 8) = s1;
}

// K1b: wh1[i] = WH[i,:]·a[:64], wh2[i] = WH[i,:]·a[64:]
__global__ void k_wh12(const float* __restrict__ WH, const float* __restrict__ a,
                       float* __restrict__ wh1, float* __restrict__ wh2) {
    int row = blockIdx.x * 256 + threadIdx.x;
    float s1 = 0.f, s2 = 0.f;
#pragma unroll 8
    for (int f = 0; f < OUT_F; f++) {
        float v = WH[row * OUT_F + f];
        s1 += v * a[f];
        s2 += v * a[OUT_F + f];
    }
    wh1[row] = s1;
    wh2[row] = s2;
}

// K2: fused mask + leaky_relu + exp + (P @ WH) partials, deterministic split
// buffers (no atomics, no memset). grid (128 row-blocks, 16 j-splits).
__global__ __launch_bounds__(256, 6) void k_attn(const int* __restrict__ adj,
                                                 const short* __restrict__ WHbT,
                                                 const float* __restrict__ wh1,
                                                 const float* __restrict__ wh2,
                                                 float* __restrict__ num_part,
                                                 float* __restrict__ den_part) {
    int w = threadIdx.x >> 6;
    int lane = threadIdx.x & 63;
    int n = lane & 15, q = lane >> 4;
    int i0 = blockIdx.x * 64 + w * 16;
    int rowA = i0 + n;                        // this lane's A-fragment row
    int split = blockIdx.y;
    int j0 = split * JT;

    const int* ap = adj + (size_t)rowA * N + j0 + q * 8;
    const float* w2p = wh2 + j0 + q * 8;
    const short* bp0 = WHbT + (size_t)n * N + j0 + q * 8;
    float my_wh1 = wh1[rowA];

    floatx4 acc[4] = {};
    float dsum = 0.f;

    // software pipeline: preload step 0
    intx4 ca0 = *(const intx4*)(ap);
    intx4 ca1 = *(const intx4*)(ap + 4);
    floatx4 cw0 = *(const floatx4*)(w2p);
    floatx4 cw1 = *(const floatx4*)(w2p + 4);

    for (int t = 0; t < JT; t += 32) {
        intx4 na0 = ca0, na1 = ca1;
        floatx4 nw0 = cw0, nw1 = cw1;
        if (t + 32 < JT) {                    // prefetch next step
            na0 = *(const intx4*)(ap + 32);
            na1 = *(const intx4*)(ap + 36);
            nw0 = *(const floatx4*)(w2p + 32);
            nw1 = *(const floatx4*)(w2p + 36);
        }
        short8 bfr[4];
#pragma unroll
        for (int b = 0; b < 4; b++)
            bfr[b] = *(const short8*)(bp0 + (size_t)b * 16 * N + t);

        float p[8];
#pragma unroll
        for (int jj = 0; jj < 8; jj++) {
            int av = (jj < 4) ? ca0[jj] : ca1[jj - 4];
            float e = my_wh1 + ((jj < 4) ? cw0[jj] : cw1[jj - 4]);
            float el = fmaxf(e, 0.01f * e);        // leaky_relu
            float pv = __expf(el);
            pv = (av > 0) ? pv : 0.f;              // adjacency mask
            p[jj] = pv;
            dsum += pv;
        }
        short8 af;
#pragma unroll
        for (int jj = 0; jj < 8; jj++) af[jj] = f2bf(p[jj]);
#pragma unroll
        for (int b = 0; b < 4; b++)
            acc[b] = __builtin_amdgcn_mfma_f32_16x16x32_bf16(af, bfr[b], acc[b], 0, 0, 0);

        ap += 32; w2p += 32;
        ca0 = na0; ca1 = na1; cw0 = nw0; cw1 = nw1;
    }

    // denominator: combine the 4 q-groups holding the same row
    dsum += __shfl_xor(dsum, 16, 64);
    dsum += __shfl_xor(dsum, 32, 64);
    if (q == 0) den_part[(size_t)split * N + rowA] = dsum;

    // numerator partials: C/D layout row = q*4+reg, col = b*16+n
    float* np_ = num_part + (size_t)split * N * OUT_F;
#pragma unroll
    for (int b = 0; b < 4; b++)
#pragma unroll
        for (int r = 0; r < 4; r++)
            np_[(i0 + q * 4 + r) * OUT_F + b * 16 + n] = acc[b][r];
}

// K3: out = elu( (Σ num_part) / (Σ den_part) )
__global__ void k_final(const float* __restrict__ num_part,
                        const float* __restrict__ den_part,
                        float* __restrict__ out) {
    int idx = blockIdx.x * 256 + threadIdx.x;   // 524288 total
    int row = idx >> 6;
    float s = 0.f, d = 0.f;
#pragma unroll
    for (int sp = 0; sp < S_SPLIT; sp++) {
        s += num_part[(size_t)sp * N * OUT_F + idx];
        d += den_part[sp * N + row];
    }
    float x = s / d;
    out[idx] = (x > 0.f) ? x : (__expf(x) - 1.f);
}

extern "C" void kernel_launch(void* const* d_in, const int* in_sizes, int n_in,
                              void* d_out, int out_size, void* d_ws, size_t ws_size,
                              hipStream_t stream) {
    const float* h = (const float*)d_in[0];
    const int* adj = (const int*)d_in[1];
    const float* W = (const float*)d_in[2];
    const float* a = (const float*)d_in[3];
    float* out = (float*)d_out;

    char* ws = (char*)d_ws;
    float* WH    = (float*)(ws);                                   // 2 MB
    short* WHbT  = (short*)(ws + (size_t)(2 << 20));                // 1 MB
    short* WT    = (short*)(ws + (size_t)(3 << 20));                // 64 KB
    float* wh1   = (float*)(ws + (size_t)(3 << 20) + (64 << 10));   // 32 KB
    float* wh2   = wh1 + N;                                         // 32 KB
    float* num_p = (float*)(ws + (size_t)(4 << 20));                // 16 x 2 MB
    float* den_p = (float*)(ws + (size_t)(36 << 20));               // 16 x 32 KB

    k_wt<<<dim3(128), dim3(256), 0, stream>>>(W, WT);
    k_wh<<<dim3(N / 16), dim3(64), 0, stream>>>(h, WT, WH, WHbT);
    k_wh12<<<dim3(N / 256), dim3(256), 0, stream>>>(WH, a, wh1, wh2);
    k_attn<<<dim3(128, S_SPLIT), dim3(256), 0, stream>>>(adj, WHbT, wh1, wh2, num_p, den_p);
    k_final<<<dim3((N * OUT_F) / 256), dim3(256), 0, stream>>>(num_p, den_p, out);
}